// Round 13
// baseline (1529.895 us; speedup 1.0000x reference)
//
#include <hip/hip_runtime.h>

#define T_ 1024
#define B_ 128
#define H_ 128
#define L_ 20
#define G4H_ 512
#define NCH 8              // batch chunks of 16 rows
#define RING 64            // ring depth (steps)
#define GRP 8              // flag granularity (steps)  [R13: was 4]
#define FSTRIDE 32         // flag padding: 32 ints = 128 B
#define LEAD 12            // initial producer lead (steps)

typedef _Float16 f16x8 __attribute__((ext_vector_type(8)));
typedef _Float16 f16x4 __attribute__((ext_vector_type(4)));
typedef float f32x4 __attribute__((ext_vector_type(4)));

__device__ __forceinline__ float fast_sig(float x) {
  float e = __builtin_amdgcn_exp2f(-1.44269504f * x);
  return __builtin_amdgcn_rcpf(1.0f + e);
}
__device__ __forceinline__ float fast_tanh(float x) {
  float e = __builtin_amdgcn_exp2f(2.88539008f * x);
  return 1.0f - 2.0f * __builtin_amdgcn_rcpf(e + 1.0f);
}

#define VMW(n) asm volatile("s_waitcnt vmcnt(" #n ")" ::: "memory")
#define LGKM0() asm volatile("s_waitcnt lgkmcnt(0)" ::: "memory")

// ---- device-scope (sc1) ops: serviced at LLC, no L2 wb/inv ----
__device__ __forceinline__ int flag_ld(const int* p) {  // blocking
  int r;
  asm volatile("global_load_dword %0, %1, off sc1\n\ts_waitcnt vmcnt(0)"
               : "=v"(r) : "v"(p) : "memory");
  return r;
}
__device__ __forceinline__ void flag_issue(int* d, const int* p) {  // issue only
  asm volatile("global_load_dword %0, %1, off sc1" : "=&v"(*d) : "v"(p) : "memory");
}
__device__ __forceinline__ void flag_st(int* p, int v) {
  asm volatile("global_store_dword %0, %1, off sc1" :: "v"(p), "v"(v) : "memory");
}
__device__ __forceinline__ void ld16_sc1(f16x8* d, const _Float16* p) {  // issue only
  asm volatile("global_load_dwordx4 %0, %1, off sc1" : "=&v"(*d) : "v"(p) : "memory");
}
__device__ __forceinline__ void ld16_plain(f16x8* d, const _Float16* p) {
  asm volatile("global_load_dwordx4 %0, %1, off" : "=&v"(*d) : "v"(p) : "memory");
}
__device__ __forceinline__ void st8_sc1(_Float16* p, f16x4 v) {
  asm volatile("global_store_dwordx2 %0, %1, off sc1" :: "v"(p), "v"(v) : "memory");
}
__device__ __forceinline__ void st16_plain(float* p, f32x4 v) {
  asm volatile("global_store_dwordx4 %0, %1, off" :: "v"(p), "v"(v) : "memory");
}

__global__ void wconv_kernel(const float* __restrict__ Wih, const float* __restrict__ Whh,
                             _Float16* __restrict__ Wif, _Float16* __restrict__ Whf) {
  int i = blockIdx.x * 256 + threadIdx.x;
  if (i < L_ * G4H_ * H_) {
    Wif[i] = (_Float16)Wih[i];
    Whf[i] = (_Float16)Whh[i];
  }
}

// Embedding: fp32 row-major copy to d_out + fp16 FRAGMENT-ORDER copy to X0.
// FIDX(b,k) = (k>>5)*512 + (((k>>3)&3)*16 + b)*8 + (k&7)   (16x128 tile)
__global__ void emb_kernel(const int* __restrict__ xids, const float* __restrict__ emb,
                           float* __restrict__ out_emb, _Float16* __restrict__ X0) {
  int row = blockIdx.x;        // t*B + b
  int d = threadIdx.x;         // k
  int t = row >> 7, b = row & 127;
  int tok = xids[row];
  float v = emb[(size_t)tok * H_ + d];
  out_emb[(size_t)row * H_ + d] = v;
  int fidx = ((d >> 5) << 9) | (((((d >> 3) & 3) << 4) | (b & 15)) << 3) | (d & 7);
  X0[((size_t)t * NCH + (b >> 4)) * 2048 + fidx] = (_Float16)v;
}

// R13 = R9 (last PASS, 1444us) + GRP=8 + cross-wave ps diagnostic:
//   G=0 input-GEMM tile is computed by the NEIGHBOR wave (w computes tile of
//   wave (w+1)&7, using that wave's Wih G=0 rows + bias), written to ps with
//   R10's exact indexing, and read back cross-wave one barrier later.
//   Values are mathematically identical -> absmax must be exactly 4.8828e-4.
//   Any deviation convicts the ps addressing/cadence used in R10-R12.
__launch_bounds__(512, 2)
__global__ void lstm_persist_kernel(const _Float16* __restrict__ Wif,
                                    const _Float16* __restrict__ Whf,
                                    const float* __restrict__ bih,
                                    const float* __restrict__ bhh,
                                    const _Float16* __restrict__ X0,
                                    _Float16* __restrict__ XR,
                                    float* __restrict__ out_h,
                                    int* __restrict__ rdy) {
  const int l = blockIdx.x >> 3;
  const int chunk = blockIdx.x & 7;
  const int tid = threadIdx.x;
  const int lane = tid & 63;
  const int wave = tid >> 6;
  const int wn = (wave + 1) & 7;   // neighbor wave: whose G=0 tile we compute
  const int lr = lane & 15;    // A row (hidden j) / B col (batch) / D col
  const int lhi = lane >> 4;   // k-subgroup; D row group
  const int ub = wave * 16;
  const int hk = ub + lhi * 4; // this lane's 4 produced hidden k's
  const int hdst = ((hk >> 5) << 9) + (((((hk >> 3) & 3) << 4) + lr) << 3) + ((lhi & 1) << 2);

  // ---- weight fragments (A-operand): wi G=0 rows come from NEIGHBOR's slice
  f16x8 wi[4][4], wh[4][4];
  f32x4 bias4[4];
  {
    const _Float16* wip = Wif + (size_t)l * G4H_ * H_;
    const _Float16* whp = Whf + (size_t)l * G4H_ * H_;
#pragma unroll
    for (int G = 0; G < 4; ++G) {
      int jh = G * 128 + ub + lr;                               // Whh rows: own
      int ji = (G == 0) ? (wn * 16 + lr) : jh;                  // Wih G=0: neighbor
#pragma unroll
      for (int kt = 0; kt < 4; ++kt) {
        wi[G][kt] = *(const f16x8*)(wip + (size_t)ji * H_ + kt * 32 + lhi * 8);
        wh[G][kt] = *(const f16x8*)(whp + (size_t)jh * H_ + kt * 32 + lhi * 8);
      }
      int jb = (G == 0) ? (wn * 16 + lhi * 4) : (G * 128 + ub + lhi * 4);
      bias4[G] = *(const f32x4*)&bih[l * G4H_ + jb];
      bias4[G] += *(const f32x4*)&bhh[l * G4H_ + jb];
    }
  }

  __shared__ __align__(16) _Float16 hs[2][2048];  // fragment-order h exchange
  __shared__ __align__(16) float ps[4][2048];     // G=0 P handoff (R10 formula, G=0 region)

  const _Float16* ring_in =
      (l > 0) ? XR + (size_t)((l - 1) * NCH + chunk) * (RING * 2048) : (const _Float16*)0;
  _Float16* ring_out = XR + (size_t)(l * NCH + chunk) * (RING * 2048);

  int* rout = rdy + (l * NCH + chunk) * FSTRIDE;
  const int* rin = (l > 0) ? rdy + ((l - 1) * NCH + chunk) * FSTRIDE : rout;
  const int* rcons = (l < L_ - 1) ? rdy + ((l + 1) * NCH + chunk) * FSTRIDE : rout;

  f16x8 xf[4];       // x fragments, single logical buffer
  int fR = 0, fC = 0;

#define XISSUE(t_) {                                                              \
    if (l == 0) {                                                                 \
      const _Float16* bp = X0 + ((size_t)(t_) * NCH + chunk) * 2048 + lane * 8;   \
      ld16_plain(&xf[0], bp);       ld16_plain(&xf[1], bp + 512);                 \
      ld16_plain(&xf[2], bp + 1024); ld16_plain(&xf[3], bp + 1536);               \
    } else {                                                                      \
      const _Float16* bp = ring_in + (size_t)((t_) & (RING - 1)) * 2048 + lane * 8; \
      ld16_sc1(&xf[0], bp);       ld16_sc1(&xf[1], bp + 512);                     \
      ld16_sc1(&xf[2], bp + 1024); ld16_sc1(&xf[3], bp + 1536);                   \
    } }

  // ---------- prologue ----------
  if (l > 0) {
    int v = 0;
    while ((v = flag_ld(rin)) < LEAD) __builtin_amdgcn_s_sleep(2);
    fR = v;
  }
  float cst[4] = {0.f, 0.f, 0.f, 0.f};
  f32x4 a0[4], a1[4];
  XISSUE(0);
  VMW(0);
  __builtin_amdgcn_sched_barrier(0);
#pragma unroll
  for (int G = 0; G < 4; ++G) a0[G] = bias4[G];
#pragma unroll
  for (int kt = 0; kt < 4; ++kt)
#pragma unroll
    for (int G = 0; G < 4; ++G)
      a0[G] = __builtin_amdgcn_mfma_f32_16x16x32_f16(wi[G][kt], xf[kt], a0[G], 0, 0, 0);
  XISSUE(1);                      // 4 loads in flight
  flag_issue(&fR, rin);           // +2 flag loads (newest)
  flag_issue(&fC, rcons);
  // publish neighbor's G=0 P(0) tile; seal before STEP(0) reads cross-wave
  *(f32x4*)&ps[0][wn * 256 + lane * 4] = a0[0];
  LGKM0();
  __builtin_amdgcn_s_barrier();
  asm volatile("" ::: "memory");

// One step. AC = bias+Wih·x_t (regs; G=0 component REPLACED from ps cross-wave);
// AN <- bias+Wih·x_{t+1}; AN[0] also published to ps for wave w-1's read.
#define STEP(t_, AC, AN, VMN) {                                                   \
    const int t = (t_);                                                           \
    AC[0] = *(const f32x4*)&ps[t & 3][wave * 256 + lane * 4]; /* cross-wave */    \
    if (t > 0) { /* hidden GEMM from LDS */                                       \
      f16x8 hf0 = *(const f16x8*)&hs[(t - 1) & 1][lane * 8];                      \
      f16x8 hf1 = *(const f16x8*)&hs[(t - 1) & 1][512 + lane * 8];                \
      f16x8 hf2 = *(const f16x8*)&hs[(t - 1) & 1][1024 + lane * 8];               \
      f16x8 hf3 = *(const f16x8*)&hs[(t - 1) & 1][1536 + lane * 8];               \
      _Pragma("unroll")                                                           \
      for (int G = 0; G < 4; ++G) {                                               \
        AC[G] = __builtin_amdgcn_mfma_f32_16x16x32_f16(wh[G][0], hf0, AC[G], 0, 0, 0); \
        AC[G] = __builtin_amdgcn_mfma_f32_16x16x32_f16(wh[G][1], hf1, AC[G], 0, 0, 0); \
        AC[G] = __builtin_amdgcn_mfma_f32_16x16x32_f16(wh[G][2], hf2, AC[G], 0, 0, 0); \
        AC[G] = __builtin_amdgcn_mfma_f32_16x16x32_f16(wh[G][3], hf3, AC[G], 0, 0, 0); \
      }                                                                           \
    }                                                                             \
    if (t + 1 < T_) { /* input GEMM for t+1 from xf regs */                       \
      VMW(VMN);                                                                   \
      __builtin_amdgcn_sched_barrier(0);                                          \
      _Pragma("unroll")                                                           \
      for (int G = 0; G < 4; ++G) AN[G] = bias4[G];                               \
      _Pragma("unroll")                                                           \
      for (int kt = 0; kt < 4; ++kt)                                              \
        _Pragma("unroll")                                                         \
        for (int G = 0; G < 4; ++G)                                               \
          AN[G] = __builtin_amdgcn_mfma_f32_16x16x32_f16(wi[G][kt], xf[kt], AN[G], 0, 0, 0); \
      *(f32x4*)&ps[(t + 1) & 3][wn * 256 + lane * 4] = AN[0]; /* publish */       \
    }                                                                             \
    if (t + 2 < T_) XISSUE(t + 2); /* 4 loads (WAR on xf keeps order) */          \
    float hnew[4];                                                                \
    _Pragma("unroll")                                                             \
    for (int r = 0; r < 4; ++r) {                                                 \
      float iv = fast_sig(AC[0][r]);                                              \
      float fv = fast_sig(AC[1][r]);                                              \
      float gv = fast_tanh(AC[2][r]);                                             \
      float ov = fast_sig(AC[3][r]);                                              \
      float c = fv * cst[r] + iv * gv;                                            \
      cst[r] = c;                                                                 \
      hnew[r] = ov * fast_tanh(c);                                                \
    }                                                                             \
    f16x4 hp;                                                                     \
    _Pragma("unroll")                                                             \
    for (int r = 0; r < 4; ++r) hp[r] = (_Float16)hnew[r];                        \
    if (l < L_ - 1) { /* coalesced fragment-order ring store, 8B/lane */          \
      st8_sc1(ring_out + (size_t)(t & (RING - 1)) * 2048 + hdst, hp);             \
    } else { /* fp32 output, row-major */                                         \
      f32x4 ov4;                                                                  \
      _Pragma("unroll")                                                           \
      for (int r = 0; r < 4; ++r) ov4[r] = hnew[r];                               \
      st16_plain(out_h + ((size_t)t * B_ + chunk * 16 + lr) * H_ + hk, ov4);      \
    }                                                                             \
    *(f16x4*)&hs[t & 1][hdst] = hp;                                               \
    LGKM0();                                                                      \
    __builtin_amdgcn_s_barrier();                                                 \
    asm volatile("" ::: "memory");                                                \
  }

  // ---------- group 0 (8 steps) ----------
  STEP(0, a0, a1, 2)   // leaves the 2 prologue flag loads outstanding
  STEP(1, a1, a0, 1)
  STEP(2, a0, a1, 1)
  STEP(3, a1, a0, 1)
  STEP(4, a0, a1, 1)
  STEP(5, a1, a0, 1)
  STEP(6, a0, a1, 1)
  STEP(7, a1, a0, 1)

  // ---------- main groups ----------
  for (int tg = GRP; tg < T_; tg += GRP) {
    VMW(0);                          // drain: ring stores, x loads, flag loads
    __builtin_amdgcn_s_barrier();    // all waves drained
    asm volatile("" ::: "memory");
    if (tid == 0) flag_st(rout, tg); // certify steps < tg
    if (l > 0) {                     // license x(tg+2..tg+GRP+1) direct loads
      int need = tg + GRP + 2; if (need > T_) need = T_;
      while (fR < need) { fR = flag_ld(rin); __builtin_amdgcn_s_sleep(2); }
    }
    if (l < L_ - 1) {                // ring slot-reuse backpressure (margin 8)
      int need = tg - 48;
      if (need > 0)
        while (fC < need) { fC = flag_ld(rcons); __builtin_amdgcn_s_sleep(2); }
    }
    flag_issue(&fR, rin);            // for NEXT boundary (drained by its VMW(0))
    flag_issue(&fC, rcons);
    STEP(tg, a0, a1, 3)              // boundary drained; leave 3 flag ops
    STEP(tg + 1, a1, a0, 1)
    STEP(tg + 2, a0, a1, 1)
    STEP(tg + 3, a1, a0, 1)
    STEP(tg + 4, a0, a1, 1)
    STEP(tg + 5, a1, a0, 1)
    STEP(tg + 6, a0, a1, 1)
    STEP(tg + 7, a1, a0, 1)
  }

  // ---------- epilogue ----------
  __syncthreads();                   // full drain: last stores at LLC
  if (tid == 0) flag_st(rout, T_);
}

extern "C" void kernel_launch(void* const* d_in, const int* in_sizes, int n_in,
                              void* d_out, int out_size, void* d_ws, size_t ws_size,
                              hipStream_t stream) {
  const int* xids = (const int*)d_in[0];
  const float* emb = (const float*)d_in[1];
  const float* Wih = (const float*)d_in[2];
  const float* Whh = (const float*)d_in[3];
  const float* bih = (const float*)d_in[4];
  const float* bhh = (const float*)d_in[5];
  float* out = (float*)d_out;
  float* out_h = out;                              // output 0: [T,B,H]
  float* out_emb = out + (size_t)T_ * B_ * H_;     // output 1: [T,B,H]

  char* ws = (char*)d_ws;
  const size_t RDY_BYTES = (size_t)L_ * NCH * FSTRIDE * 4;
  const size_t X0_BYTES = (size_t)T_ * B_ * H_ * 2;
  const size_t XR_BYTES = (size_t)L_ * NCH * RING * 2048 * 2;
  const size_t WF_BYTES = (size_t)L_ * G4H_ * H_ * 2;
  int* rdyp = (int*)ws;
  _Float16* X0 = (_Float16*)(ws + RDY_BYTES);
  _Float16* XR = (_Float16*)(ws + RDY_BYTES + X0_BYTES);
  _Float16* Wif = (_Float16*)(ws + RDY_BYTES + X0_BYTES + XR_BYTES);
  _Float16* Whf = (_Float16*)(ws + RDY_BYTES + X0_BYTES + XR_BYTES + WF_BYTES);

  hipMemsetAsync(rdyp, 0, RDY_BYTES, stream);
  wconv_kernel<<<(L_ * G4H_ * H_ + 255) / 256, 256, 0, stream>>>(Wih, Whh, Wif, Whf);
  emb_kernel<<<T_ * B_, H_, 0, stream>>>(xids, emb, out_emb, X0);

  void* args[] = {(void*)&Wif, (void*)&Whf, (void*)&bih, (void*)&bhh,
                  (void*)&X0,  (void*)&XR,  (void*)&out_h, (void*)&rdyp};
  hipLaunchCooperativeKernel((void*)lstm_persist_kernel, dim3(L_ * NCH), dim3(512),
                             args, 0, stream);
}

// Round 14
// 1437.838 us; speedup vs baseline: 1.0640x; 1.0640x over previous
//
#include <hip/hip_runtime.h>

#define T_ 1024
#define B_ 128
#define H_ 128
#define L_ 20
#define G4H_ 512
#define NCH 8              // batch chunks of 16 rows
#define RING 64            // ring depth (steps)
#define GRP 4              // flag granularity (steps) — R9-verified ledger
#define FSTRIDE 32         // flag padding: 32 ints = 128 B
#define LEAD 12            // initial producer lead (steps)

typedef _Float16 f16x8 __attribute__((ext_vector_type(8)));
typedef _Float16 f16x4 __attribute__((ext_vector_type(4)));
typedef float f32x4 __attribute__((ext_vector_type(4)));

__device__ __forceinline__ float fast_sig(float x) {
  float e = __builtin_amdgcn_exp2f(-1.44269504f * x);
  return __builtin_amdgcn_rcpf(1.0f + e);
}
__device__ __forceinline__ float fast_tanh(float x) {
  float e = __builtin_amdgcn_exp2f(2.88539008f * x);
  return 1.0f - 2.0f * __builtin_amdgcn_rcpf(e + 1.0f);
}

#define VMW(n) asm volatile("s_waitcnt vmcnt(" #n ")" ::: "memory")
#define LGKM0() asm volatile("s_waitcnt lgkmcnt(0)" ::: "memory")

// ---- device-scope (sc1) ops: serviced at LLC, no L2 wb/inv ----
__device__ __forceinline__ int flag_ld(const int* p) {  // blocking
  int r;
  asm volatile("global_load_dword %0, %1, off sc1\n\ts_waitcnt vmcnt(0)"
               : "=v"(r) : "v"(p) : "memory");
  return r;
}
__device__ __forceinline__ void flag_issue(int* d, const int* p) {  // issue only
  asm volatile("global_load_dword %0, %1, off sc1" : "=&v"(*d) : "v"(p) : "memory");
}
__device__ __forceinline__ void flag_st(int* p, int v) {
  asm volatile("global_store_dword %0, %1, off sc1" :: "v"(p), "v"(v) : "memory");
}
__device__ __forceinline__ void ld16_sc1(f16x8* d, const _Float16* p) {  // issue only
  asm volatile("global_load_dwordx4 %0, %1, off sc1" : "=&v"(*d) : "v"(p) : "memory");
}
__device__ __forceinline__ void ld16_plain(f16x8* d, const _Float16* p) {
  asm volatile("global_load_dwordx4 %0, %1, off" : "=&v"(*d) : "v"(p) : "memory");
}
__device__ __forceinline__ void st8_sc1(_Float16* p, f16x4 v) {
  asm volatile("global_store_dwordx2 %0, %1, off sc1" :: "v"(p), "v"(v) : "memory");
}
__device__ __forceinline__ void st16_plain(float* p, f32x4 v) {
  asm volatile("global_store_dwordx4 %0, %1, off" :: "v"(p), "v"(v) : "memory");
}

__global__ void wconv_kernel(const float* __restrict__ Wih, const float* __restrict__ Whh,
                             _Float16* __restrict__ Wif, _Float16* __restrict__ Whf) {
  int i = blockIdx.x * 256 + threadIdx.x;
  if (i < L_ * G4H_ * H_) {
    Wif[i] = (_Float16)Wih[i];
    Whf[i] = (_Float16)Whh[i];
  }
}

// Embedding: fp32 row-major copy to d_out + fp16 FRAGMENT-ORDER copy to X0.
// FIDX(b,k) = (k>>5)*512 + (((k>>3)&3)*16 + b)*8 + (k&7)   (16x128 tile)
__global__ void emb_kernel(const int* __restrict__ xids, const float* __restrict__ emb,
                           float* __restrict__ out_emb, _Float16* __restrict__ X0) {
  int row = blockIdx.x;        // t*B + b
  int d = threadIdx.x;         // k
  int t = row >> 7, b = row & 127;
  int tok = xids[row];
  float v = emb[(size_t)tok * H_ + d];
  out_emb[(size_t)row * H_ + d] = v;
  int fidx = ((d >> 5) << 9) | (((((d >> 3) & 3) << 4) | (b & 15)) << 3) | (d & 7);
  X0[((size_t)t * NCH + (b >> 4)) * 2048 + fidx] = (_Float16)v;
}

// R14 = R9 (best PASS, 1444us) with ONE change: input GEMM(t+1) reordered
// BEFORE hidden GEMM(t). Input GEMM has no LDS dependence, so its 16 MFMAs
// execute while the 4 hf ds_reads are in flight; the compiler's lgkmcnt wait
// moves from right-after-issue to the hidden GEMM. VM issue order unchanged
// -> vmcnt ledger identical to the twice-verified R9 protocol.
__launch_bounds__(512, 2)
__global__ void lstm_persist_kernel(const _Float16* __restrict__ Wif,
                                    const _Float16* __restrict__ Whf,
                                    const float* __restrict__ bih,
                                    const float* __restrict__ bhh,
                                    const _Float16* __restrict__ X0,
                                    _Float16* __restrict__ XR,
                                    float* __restrict__ out_h,
                                    int* __restrict__ rdy) {
  const int l = blockIdx.x >> 3;
  const int chunk = blockIdx.x & 7;
  const int tid = threadIdx.x;
  const int lane = tid & 63;
  const int wave = tid >> 6;
  const int lr = lane & 15;    // A row (hidden j) / B col (batch) / D col
  const int lhi = lane >> 4;   // k-subgroup; D row group
  const int ub = wave * 16;
  const int hk = ub + lhi * 4; // this lane's 4 produced hidden k's
  const int hdst = ((hk >> 5) << 9) + (((((hk >> 3) & 3) << 4) + lr) << 3) + ((lhi & 1) << 2);

  // ---- weight fragments (A-operand, R7-verified): W[j=G*128+ub+lr][kt*32+lhi*8..+8]
  f16x8 wi[4][4], wh[4][4];
  f32x4 bias4[4];
  {
    const _Float16* wip = Wif + (size_t)l * G4H_ * H_;
    const _Float16* whp = Whf + (size_t)l * G4H_ * H_;
#pragma unroll
    for (int G = 0; G < 4; ++G) {
      int j = G * 128 + ub + lr;
#pragma unroll
      for (int kt = 0; kt < 4; ++kt) {
        wi[G][kt] = *(const f16x8*)(wip + (size_t)j * H_ + kt * 32 + lhi * 8);
        wh[G][kt] = *(const f16x8*)(whp + (size_t)j * H_ + kt * 32 + lhi * 8);
      }
      int jb = G * 128 + ub + lhi * 4;
      bias4[G] = *(const f32x4*)&bih[l * G4H_ + jb];
      bias4[G] += *(const f32x4*)&bhh[l * G4H_ + jb];
    }
  }

  __shared__ __align__(16) _Float16 hs[2][2048];  // fragment-order h exchange

  const _Float16* ring_in =
      (l > 0) ? XR + (size_t)((l - 1) * NCH + chunk) * (RING * 2048) : (const _Float16*)0;
  _Float16* ring_out = XR + (size_t)(l * NCH + chunk) * (RING * 2048);

  int* rout = rdy + (l * NCH + chunk) * FSTRIDE;
  const int* rin = (l > 0) ? rdy + ((l - 1) * NCH + chunk) * FSTRIDE : rout;
  const int* rcons = (l < L_ - 1) ? rdy + ((l + 1) * NCH + chunk) * FSTRIDE : rout;

  f16x8 xf[4];       // x fragments, single logical buffer
  int fR = 0, fC = 0;

#define XISSUE(t_) {                                                              \
    if (l == 0) {                                                                 \
      const _Float16* bp = X0 + ((size_t)(t_) * NCH + chunk) * 2048 + lane * 8;   \
      ld16_plain(&xf[0], bp);       ld16_plain(&xf[1], bp + 512);                 \
      ld16_plain(&xf[2], bp + 1024); ld16_plain(&xf[3], bp + 1536);               \
    } else {                                                                      \
      const _Float16* bp = ring_in + (size_t)((t_) & (RING - 1)) * 2048 + lane * 8; \
      ld16_sc1(&xf[0], bp);       ld16_sc1(&xf[1], bp + 512);                     \
      ld16_sc1(&xf[2], bp + 1024); ld16_sc1(&xf[3], bp + 1536);                   \
    } }

  // ---------- prologue ----------
  if (l > 0) {
    int v = 0;
    while ((v = flag_ld(rin)) < LEAD) __builtin_amdgcn_s_sleep(2);
    fR = v;
  }
  float cst[4] = {0.f, 0.f, 0.f, 0.f};
  f32x4 a0[4], a1[4];
  XISSUE(0);
  VMW(0);
  __builtin_amdgcn_sched_barrier(0);
#pragma unroll
  for (int G = 0; G < 4; ++G) a0[G] = bias4[G];
#pragma unroll
  for (int kt = 0; kt < 4; ++kt)
#pragma unroll
    for (int G = 0; G < 4; ++G)
      a0[G] = __builtin_amdgcn_mfma_f32_16x16x32_f16(wi[G][kt], xf[kt], a0[G], 0, 0, 0);
  XISSUE(1);                      // 4 loads in flight
  flag_issue(&fR, rin);           // +2 flag loads (newest)
  flag_issue(&fC, rcons);

// One step. AC = bias+Wih·x_t (pre-filled); AN <- bias+Wih·x_{t+1} from xf.
// Order: issue hf ds_reads -> input GEMM(t+1) (no LDS dep; hides ds_read
// latency) -> hidden GEMM(t) -> XISSUE(t+2) -> gates -> stores -> barrier.
#define STEP(t_, AC, AN, VMN) {                                                   \
    const int t = (t_);                                                           \
    f16x8 hf0, hf1, hf2, hf3;                                                     \
    if (t > 0) { /* issue hf ds_reads early */                                    \
      hf0 = *(const f16x8*)&hs[(t - 1) & 1][lane * 8];                            \
      hf1 = *(const f16x8*)&hs[(t - 1) & 1][512 + lane * 8];                      \
      hf2 = *(const f16x8*)&hs[(t - 1) & 1][1024 + lane * 8];                     \
      hf3 = *(const f16x8*)&hs[(t - 1) & 1][1536 + lane * 8];                     \
    }                                                                             \
    if (t + 1 < T_) { /* input GEMM for t+1 from xf regs (overlaps hf reads) */   \
      VMW(VMN);                                                                   \
      __builtin_amdgcn_sched_barrier(0);                                          \
      _Pragma("unroll")                                                           \
      for (int G = 0; G < 4; ++G) AN[G] = bias4[G];                               \
      _Pragma("unroll")                                                           \
      for (int kt = 0; kt < 4; ++kt)                                              \
        _Pragma("unroll")                                                         \
        for (int G = 0; G < 4; ++G)                                               \
          AN[G] = __builtin_amdgcn_mfma_f32_16x16x32_f16(wi[G][kt], xf[kt], AN[G], 0, 0, 0); \
    }                                                                             \
    if (t > 0) { /* hidden GEMM (lgkm wait lands here) */                         \
      _Pragma("unroll")                                                           \
      for (int G = 0; G < 4; ++G) {                                               \
        AC[G] = __builtin_amdgcn_mfma_f32_16x16x32_f16(wh[G][0], hf0, AC[G], 0, 0, 0); \
        AC[G] = __builtin_amdgcn_mfma_f32_16x16x32_f16(wh[G][1], hf1, AC[G], 0, 0, 0); \
        AC[G] = __builtin_amdgcn_mfma_f32_16x16x32_f16(wh[G][2], hf2, AC[G], 0, 0, 0); \
        AC[G] = __builtin_amdgcn_mfma_f32_16x16x32_f16(wh[G][3], hf3, AC[G], 0, 0, 0); \
      }                                                                           \
    }                                                                             \
    if (t + 2 < T_) XISSUE(t + 2); /* 4 loads (WAR on xf keeps order) */          \
    float hnew[4];                                                                \
    _Pragma("unroll")                                                             \
    for (int r = 0; r < 4; ++r) {                                                 \
      float iv = fast_sig(AC[0][r]);                                              \
      float fv = fast_sig(AC[1][r]);                                              \
      float gv = fast_tanh(AC[2][r]);                                             \
      float ov = fast_sig(AC[3][r]);                                              \
      float c = fv * cst[r] + iv * gv;                                            \
      cst[r] = c;                                                                 \
      hnew[r] = ov * fast_tanh(c);                                                \
    }                                                                             \
    f16x4 hp;                                                                     \
    _Pragma("unroll")                                                             \
    for (int r = 0; r < 4; ++r) hp[r] = (_Float16)hnew[r];                        \
    if (l < L_ - 1) { /* coalesced fragment-order ring store, 8B/lane */          \
      st8_sc1(ring_out + (size_t)(t & (RING - 1)) * 2048 + hdst, hp);             \
    } else { /* fp32 output, row-major */                                         \
      f32x4 ov4;                                                                  \
      _Pragma("unroll")                                                           \
      for (int r = 0; r < 4; ++r) ov4[r] = hnew[r];                               \
      st16_plain(out_h + ((size_t)t * B_ + chunk * 16 + lr) * H_ + hk, ov4);      \
    }                                                                             \
    *(f16x4*)&hs[t & 1][hdst] = hp;                                               \
    LGKM0();                                                                      \
    __builtin_amdgcn_s_barrier();                                                 \
    asm volatile("" ::: "memory");                                                \
  }

  // ---------- group 0 ----------
  STEP(0, a0, a1, 2)   // leaves the 2 prologue flag loads outstanding
  STEP(1, a1, a0, 1)
  STEP(2, a0, a1, 1)
  STEP(3, a1, a0, 1)

  // ---------- main groups ----------
  for (int tg = GRP; tg < T_; tg += GRP) {
    VMW(0);                          // drain: ring stores, x loads, flag loads
    __builtin_amdgcn_s_barrier();    // all waves drained
    asm volatile("" ::: "memory");
    if (tid == 0) flag_st(rout, tg); // certify steps < tg
    if (l > 0) {                     // license x(tg+2..tg+5) direct loads
      int need = tg + GRP + 2; if (need > T_) need = T_;
      while (fR < need) { fR = flag_ld(rin); __builtin_amdgcn_s_sleep(2); }
    }
    if (l < L_ - 1) {                // ring slot-reuse backpressure
      int need = tg - 52;
      if (need > 0)
        while (fC < need) { fC = flag_ld(rcons); __builtin_amdgcn_s_sleep(2); }
    }
    flag_issue(&fR, rin);            // for NEXT boundary (drained by its VMW(0))
    flag_issue(&fC, rcons);
    STEP(tg, a0, a1, 3)              // no xf wait needed (boundary drained)
    STEP(tg + 1, a1, a0, 1)
    STEP(tg + 2, a0, a1, 1)
    STEP(tg + 3, a1, a0, 1)
  }

  // ---------- epilogue ----------
  __syncthreads();                   // full drain: last stores at LLC
  if (tid == 0) flag_st(rout, T_);
}

extern "C" void kernel_launch(void* const* d_in, const int* in_sizes, int n_in,
                              void* d_out, int out_size, void* d_ws, size_t ws_size,
                              hipStream_t stream) {
  const int* xids = (const int*)d_in[0];
  const float* emb = (const float*)d_in[1];
  const float* Wih = (const float*)d_in[2];
  const float* Whh = (const float*)d_in[3];
  const float* bih = (const float*)d_in[4];
  const float* bhh = (const float*)d_in[5];
  float* out = (float*)d_out;
  float* out_h = out;                              // output 0: [T,B,H]
  float* out_emb = out + (size_t)T_ * B_ * H_;     // output 1: [T,B,H]

  char* ws = (char*)d_ws;
  const size_t RDY_BYTES = (size_t)L_ * NCH * FSTRIDE * 4;
  const size_t X0_BYTES = (size_t)T_ * B_ * H_ * 2;
  const size_t XR_BYTES = (size_t)L_ * NCH * RING * 2048 * 2;
  const size_t WF_BYTES = (size_t)L_ * G4H_ * H_ * 2;
  int* rdyp = (int*)ws;
  _Float16* X0 = (_Float16*)(ws + RDY_BYTES);
  _Float16* XR = (_Float16*)(ws + RDY_BYTES + X0_BYTES);
  _Float16* Wif = (_Float16*)(ws + RDY_BYTES + X0_BYTES + XR_BYTES);
  _Float16* Whf = (_Float16*)(ws + RDY_BYTES + X0_BYTES + XR_BYTES + WF_BYTES);

  hipMemsetAsync(rdyp, 0, RDY_BYTES, stream);
  wconv_kernel<<<(L_ * G4H_ * H_ + 255) / 256, 256, 0, stream>>>(Wih, Whh, Wif, Whf);
  emb_kernel<<<T_ * B_, H_, 0, stream>>>(xids, emb, out_emb, X0);

  void* args[] = {(void*)&Wif, (void*)&Whf, (void*)&bih, (void*)&bhh,
                  (void*)&X0,  (void*)&XR,  (void*)&out_h, (void*)&rdyp};
  hipLaunchCooperativeKernel((void*)lstm_persist_kernel, dim3(L_ * NCH), dim3(512),
                             args, 0, stream);
}